// Round 10
// baseline (194.206 us; speedup 1.0000x reference)
//
#include <hip/hip_runtime.h>
#include <hip/hip_bf16.h>

typedef unsigned short ushort_t;
typedef __bf16 bf16_t;
typedef bf16_t bf16x8 __attribute__((ext_vector_type(8)));
typedef float f32x4 __attribute__((ext_vector_type(4)));
typedef float f32x16 __attribute__((ext_vector_type(16)));

#define CH 512
#define NSP 1024  // H*W

__device__ __forceinline__ float bf2f(ushort_t u) {
    union { unsigned int i; float f; } t; t.i = ((unsigned int)u) << 16; return t.f;
}
__device__ __forceinline__ ushort_t f2bf(float f) {
    union { float fl; unsigned int i; } t; t.fl = f;
    unsigned int r = t.i + 0x7fffu + ((t.i >> 16) & 1u);  // RNE
    return (ushort_t)(r >> 16);
}
// packed RNE f32x2 -> bf16x2 (v_cvt_pk_bf16_f32 on gfx950)
__device__ __forceinline__ unsigned int pk2(float a, float b) {
    __hip_bfloat162 h = __float22bfloat162_rn(make_float2(a, b));
    union { __hip_bfloat162 h2; unsigned int u; } t; t.h2 = h; return t.u;
}

#if __has_builtin(__builtin_amdgcn_global_load_lds)
#define HAVE_ASYNC_LDS 1
#endif
__device__ __forceinline__ void cp16(const ushort_t* g, ushort_t* l) {
#ifdef HAVE_ASYNC_LDS
    __builtin_amdgcn_global_load_lds((const __attribute__((address_space(1))) unsigned int*)g,
                                     (__attribute__((address_space(3))) unsigned int*)l, 16, 0, 0);
#else
    *(uint4*)l = *(const uint4*)g;
#endif
}

#define QSCALE 0.18033688011112042f   // 0.125 * log2(e), folded into q

// ---------------- prep: blocks 0..255 = GN stats; 256..1279 = W fp32->bf16 ----------------
__global__ __launch_bounds__(256) void prep_kernel(const float* __restrict__ x,
                                                   const float* __restrict__ w0, const float* __restrict__ w1,
                                                   const float* __restrict__ w2, const float* __restrict__ w3,
                                                   float2* __restrict__ gstats, ushort_t* __restrict__ wbf) {
    int tid = threadIdx.x;
    if (blockIdx.x >= 256) {
        int idx = (blockIdx.x - 256) * 256 + tid;   // 0..262143 float4s
        int my = idx >> 16;
        const float* src = (my == 0) ? w0 : (my == 1) ? w1 : (my == 2) ? w2 : w3;
        float4 v = reinterpret_cast<const float4*>(src)[idx & 65535];
        uint2 u = make_uint2(pk2(v.x, v.y), pk2(v.z, v.w));
        reinterpret_cast<uint2*>(wbf + (size_t)my * 262144)[idx & 65535] = u;
        return;
    }
    __shared__ float red[8];
    int bg = blockIdx.x;
    size_t base = (size_t)bg * 16384;
    float s = 0.f, s2 = 0.f;
    const float4* x4 = reinterpret_cast<const float4*>(x + base);
    for (int i = tid; i < 4096; i += 256) {
        float4 v = x4[i];
        s  += v.x + v.y + v.z + v.w;
        s2 += v.x * v.x + v.y * v.y + v.z * v.z + v.w * v.w;
    }
    #pragma unroll
    for (int off = 32; off > 0; off >>= 1) {
        s  += __shfl_down(s, off, 64);
        s2 += __shfl_down(s2, off, 64);
    }
    int wv = tid >> 6;
    if ((tid & 63) == 0) { red[wv] = s; red[4 + wv] = s2; }
    __syncthreads();
    if (tid == 0) {
        float ts  = red[0] + red[1] + red[2] + red[3];
        float ts2 = red[4] + red[5] + red[6] + red[7];
        float mu  = ts * (1.f / 16384.f);
        float var = ts2 * (1.f / 16384.f) - mu * mu;
        gstats[bg] = make_float2(mu, rsqrtf(var + 1e-5f));
    }
}

// ---------------- GroupNorm apply + transpose -> xnt [b][n][c] bf16 ----------------
__global__ __launch_bounds__(256) void gn_apply(const float* __restrict__ x, const float* __restrict__ gw,
                                                const float* __restrict__ gbias, const float2* __restrict__ gstats,
                                                ushort_t* __restrict__ xnt) {
    __shared__ __align__(16) ushort_t lt[16 * 264];
    int nq = blockIdx.x;            // 0..3 (256-col chunk)
    int bg = blockIdx.y;            // b*32+g
    int b = bg >> 5, g = bg & 31;
    int tid = threadIdx.x;
    float2 st = gstats[bg];
    float mu = st.x, rstd = st.y;
    const float4* x4 = reinterpret_cast<const float4*>(x + ((size_t)(b * 512 + g * 16) * 1024 + nq * 256));
    #pragma unroll
    for (int rep = 0; rep < 4; rep++) {
        int id = rep * 256 + tid;
        int cc = id >> 6, j = id & 63;
        float ww = gw[g * 16 + cc], bb = gbias[g * 16 + cc];
        float ca = rstd * ww, cb = bb - mu * ca;
        float4 v = x4[cc * 256 + j];
        uint2 u = make_uint2(pk2(v.x * ca + cb, v.y * ca + cb), pk2(v.z * ca + cb, v.w * ca + cb));
        *reinterpret_cast<uint2*>(&lt[cc * 264 + j * 4]) = u;
    }
    __syncthreads();
    int n = tid;
    ushort_t ov[16];
    #pragma unroll
    for (int cc = 0; cc < 16; cc++) ov[cc] = lt[cc * 264 + n];
    ushort_t* dst = xnt + ((size_t)(b * 1024 + nq * 256 + n)) * 512 + g * 16;
    *reinterpret_cast<ushort4*>(dst + 0)  = *reinterpret_cast<ushort4*>(&ov[0]);
    *reinterpret_cast<ushort4*>(dst + 4)  = *reinterpret_cast<ushort4*>(&ov[4]);
    *reinterpret_cast<ushort4*>(dst + 8)  = *reinterpret_cast<ushort4*>(&ov[8]);
    *reinterpret_cast<ushort4*>(dst + 12) = *reinterpret_cast<ushort4*>(&ov[12]);
}

// ---------------- Fused QKV conv: 128x128 tiles, batch-per-XCD swizzle ----------------
__global__ __launch_bounds__(256) void conv_qkv(const ushort_t* __restrict__ xnt,
                                                const ushort_t* __restrict__ wbf,
                                                const float* __restrict__ bq,
                                                const float* __restrict__ bk,
                                                const float* __restrict__ bv,
                                                ushort_t* __restrict__ qt,
                                                ushort_t* __restrict__ kt,
                                                ushort_t* __restrict__ vt) {
    __shared__ __align__(16) char smem[34816];
    ushort_t* als = (ushort_t*)smem;           // [128][32] 8KB
    ushort_t* bls = (ushort_t*)(smem + 8192);  // [128][32] 8KB
    int tid = threadIdx.x;
    int wave = tid >> 6, lane = tid & 63, l15 = lane & 15, quad = lane >> 4;
    int wm = wave >> 1, wn = wave & 1;
    int id = blockIdx.x;
    int b = id & 7, t = id >> 3;
    int mt = t / 12, ot = t - mt * 12;
    int m0 = mt * 128, o0 = ot * 128;
    const ushort_t* A = xnt + (size_t)b * 524288;

    f32x4 acc[4][4];
    #pragma unroll
    for (int ms = 0; ms < 4; ms++)
        #pragma unroll
        for (int ns = 0; ns < 4; ns++) acc[ms][ns] = (f32x4){0.f, 0.f, 0.f, 0.f};

    for (int k0 = 0; k0 < 512; k0 += 32) {
        #pragma unroll
        for (int rep = 0; rep < 2; rep++) {
            int cid = rep * 256 + tid;
            int r = cid >> 2, part = cid & 3;
            int sw = part ^ ((r >> 2) & 3);
            cp16(A + (size_t)(m0 + r) * 512 + k0 + sw * 8, als + (size_t)cid * 8);
            cp16(wbf + (size_t)(o0 + r) * 512 + k0 + sw * 8, bls + (size_t)cid * 8);
        }
        __syncthreads();
        bf16x8 af[4], bfr[4];
        #pragma unroll
        for (int ms = 0; ms < 4; ms++) {
            int row = wm * 64 + ms * 16 + l15;
            int slot = quad ^ ((row >> 2) & 3);
            af[ms] = *(const bf16x8*)(als + row * 32 + slot * 8);
        }
        #pragma unroll
        for (int ns = 0; ns < 4; ns++) {
            int row = wn * 64 + ns * 16 + l15;
            int slot = quad ^ ((row >> 2) & 3);
            bfr[ns] = *(const bf16x8*)(bls + row * 32 + slot * 8);
        }
        #pragma unroll
        for (int ms = 0; ms < 4; ms++)
            #pragma unroll
            for (int ns = 0; ns < 4; ns++)
                acc[ms][ns] = __builtin_amdgcn_mfma_f32_16x16x32_bf16(af[ms], bfr[ns], acc[ms][ns], 0, 0, 0);
        __syncthreads();
    }

    int seg = o0 >> 9, lo = o0 & 511;
    if (seg < 2) {
        const float* bias = seg ? bk : bq;
        ushort_t* dst = seg ? kt : qt;
        float s = seg ? 1.f : QSCALE;
        float bvv[4];
        #pragma unroll
        for (int ns = 0; ns < 4; ns++) bvv[ns] = bias[lo + wn * 64 + ns * 16 + l15];
        ushort_t* cls = (ushort_t*)smem;   // [128 n][132]
        #pragma unroll
        for (int ms = 0; ms < 4; ms++)
            #pragma unroll
            for (int ns = 0; ns < 4; ns++) {
                int col = wn * 64 + ns * 16 + l15;
                int base = (wm * 64 + ms * 16 + quad * 4) * 132 + col;
                cls[base]           = f2bf((acc[ms][ns][0] + bvv[ns]) * s);
                cls[base + 132]     = f2bf((acc[ms][ns][1] + bvv[ns]) * s);
                cls[base + 264]     = f2bf((acc[ms][ns][2] + bvv[ns]) * s);
                cls[base + 396]     = f2bf((acc[ms][ns][3] + bvv[ns]) * s);
            }
        __syncthreads();
        int h0 = lo >> 6;
        #pragma unroll
        for (int rep = 0; rep < 8; rep++) {
            int cid = rep * 256 + tid;
            int row = cid >> 4, p = cid & 15;
            int h = h0 + (p >> 3);
            size_t ga = ((size_t)(b * 8 + h) * 1024 + m0 + row) * 64 + (p & 7) * 8;
            *(uint4*)(dst + ga) = *(const uint4*)(cls + row * 132 + p * 8);
        }
    } else {
        float bvv[4];
        #pragma unroll
        for (int ns = 0; ns < 4; ns++) bvv[ns] = bv[lo + wn * 64 + ns * 16 + l15];
        ushort_t* clst = (ushort_t*)smem;  // [128 o][132] transposed
        #pragma unroll
        for (int ms = 0; ms < 4; ms++)
            #pragma unroll
            for (int ns = 0; ns < 4; ns++) {
                unsigned int ua = pk2(acc[ms][ns][0] + bvv[ns], acc[ms][ns][1] + bvv[ns]);
                unsigned int ub = pk2(acc[ms][ns][2] + bvv[ns], acc[ms][ns][3] + bvv[ns]);
                *(uint2*)(&clst[(wn * 64 + ns * 16 + l15) * 132 + wm * 64 + ms * 16 + quad * 4]) =
                    make_uint2(ua, ub);
            }
        __syncthreads();
        #pragma unroll
        for (int rep = 0; rep < 8; rep++) {
            int cid = rep * 256 + tid;
            int row = cid >> 4, p = cid & 15;
            *(uint4*)(vt + ((size_t)(b * 512 + lo + row) * 1024 + m0 + p * 8)) =
                *(const uint4*)(clst + row * 132 + p * 8);
        }
    }
}

// ---------------- MFMA flash attention v3: 32x32x16, 4-wave blocks (ih x jh), pi-permuted V ----------------
// qt (pre-scaled)/kt: [bh][n][d]; vt: [bh][d][n]; ao: [b][n][c] bf16.
// 1024 blocks (XCD-swizzled) x 256 thr. Wave (ih,jh): S^T for j in jh-half(32) x i in ih-half(32).
// No-max softmax => jh partial O/l merge is a plain add at epilogue.
// K LDS frag f=jh*4+kc: lane l elem e: K[jh*32+(l&31)][kc*16+(l>>5)*8+e]   (A-operand of S)
// V LDS frag f=dt*4+jh*2+kc2: lane l elem e: V[d=dt*32+(l&31)][j=jh*32+kc2*16+pi((l>>5)*8+e)]
//   pi(k)=(k&3)+8*((k>>2)&1)+4*(k>>3): S^T C-regs (exp'd, packed) ARE the PV A-frags (R8-validated).
__global__ __launch_bounds__(256, 4) void attn_kernel(const ushort_t* __restrict__ qt,
                                                      const ushort_t* __restrict__ kt,
                                                      const ushort_t* __restrict__ vt,
                                                      ushort_t* __restrict__ ao) {
    __shared__ __align__(16) char smem[34816];
    ushort_t* kls = (ushort_t*)smem;             // 8 KB staging
    ushort_t* vls = (ushort_t*)(smem + 8192);    // 8 KB staging
    float* obuf = (float*)smem;                  // epilogue: [2][64][66] f32 = 33792 B
    float* llds = (float*)(smem + 33792);        // [2][64] f32

    int tid = threadIdx.x;
    int wave = tid >> 6, l = tid & 63, l31 = l & 31, h = l >> 5;
    int ih = wave >> 1, jh = wave & 1;
    int id = blockIdx.x;
    int sub = id >> 3;
    int bh = (id & 7) * 8 + (sub >> 4);          // 8 bh per XCD
    int i0 = (sub & 15) * 64;
    const ushort_t* qb = qt + (size_t)bh * 65536;
    const ushort_t* kb = kt + (size_t)bh * 65536;
    const ushort_t* vb = vt + (size_t)bh * 65536;

    // Q frags (B-operand of S): Q[i0+ih*32+l31][kc*16 + h*8 + e]
    bf16x8 qf[4];
    #pragma unroll
    for (int kc = 0; kc < 4; kc++)
        qf[kc] = *(const bf16x8*)(qb + (size_t)(i0 + ih * 32 + l31) * 64 + kc * 16 + h * 8);

    f32x16 oacc[2];
    #pragma unroll
    for (int dt = 0; dt < 2; dt++)
        #pragma unroll
        for (int r = 0; r < 16; r++) oacc[dt][r] = 0.f;
    float lacc = 0.f;

    // staging chunks: ck = rep*256+tid -> row = rep*32 + (tid>>3), col-chunk dc = tid&7
    int srow0 = tid >> 3, dc = tid & 7;
    uint4 krg[2], vrg[2];
    #pragma unroll
    for (int rep = 0; rep < 2; rep++) {
        int rr = rep * 32 + srow0;
        krg[rep] = *(const uint4*)(kb + (size_t)rr * 64 + dc * 8);
        vrg[rep] = *(const uint4*)(vb + (size_t)rr * 1024 + dc * 8);
    }

    for (int jt = 0; jt < 16; jt++) {
        if (jt) __syncthreads();
        #pragma unroll
        for (int rep = 0; rep < 2; rep++) {
            int rr = rep * 32 + srow0;
            // K: frag (rr>>5)*4 + (dc>>1), lane (rr&31)+32*(dc&1)
            int fa = ((rr >> 5) * 4 + (dc >> 1)) * 64 + (rr & 31) + 32 * (dc & 1);
            *(uint4*)(kls + fa * 8) = krg[rep];
            // V (pi split): frag dt*4 + (dc>>1), halves at lane-halves, elem offset 4*(dc&1)
            int vbase = ((rr >> 5) * 4 + (dc >> 1)) * 64 + (rr & 31);
            int eg = (dc & 1) * 4;
            *(uint2*)(vls + vbase * 8 + eg)        = make_uint2(vrg[rep].x, vrg[rep].y);
            *(uint2*)(vls + (vbase + 32) * 8 + eg) = make_uint2(vrg[rep].z, vrg[rep].w);
        }
        __syncthreads();
        if (jt < 15) {
            int j0n = (jt + 1) * 64;
            #pragma unroll
            for (int rep = 0; rep < 2; rep++) {
                int rr = rep * 32 + srow0;
                krg[rep] = *(const uint4*)(kb + (size_t)(j0n + rr) * 64 + dc * 8);
                vrg[rep] = *(const uint4*)(vb + (size_t)rr * 1024 + j0n + dc * 8);
            }
        }

        // S^T = K x Q^T for this wave's 32j x 32i
        f32x16 z;
        #pragma unroll
        for (int r = 0; r < 16; r++) z[r] = 0.f;
        #pragma unroll
        for (int kc = 0; kc < 4; kc++) {
            bf16x8 kf = *(const bf16x8*)(kls + ((jh * 4 + kc) * 64 + l) * 8);
            z = __builtin_amdgcn_mfma_f32_32x32x16_bf16(kf, qf[kc], z, 0, 0, 0);
        }
        // exp + pack: regs directly become PV A-frags
        union { unsigned int u[8]; bf16x8 f[2]; } pa;
        float e[16];
        float sum = 0.f;
        #pragma unroll
        for (int r = 0; r < 16; r++) { e[r] = exp2f(z[r]); sum += e[r]; }
        lacc += sum;
        #pragma unroll
        for (int u = 0; u < 8; u++) pa.u[u] = pk2(e[2 * u], e[2 * u + 1]);

        #pragma unroll
        for (int dt = 0; dt < 2; dt++) {
            bf16x8 vf0 = *(const bf16x8*)(vls + ((dt * 4 + jh * 2 + 0) * 64 + l) * 8);
            bf16x8 vf1 = *(const bf16x8*)(vls + ((dt * 4 + jh * 2 + 1) * 64 + l) * 8);
            oacc[dt] = __builtin_amdgcn_mfma_f32_32x32x16_bf16(pa.f[0], vf0, oacc[dt], 0, 0, 0);
            oacc[dt] = __builtin_amdgcn_mfma_f32_32x32x16_bf16(pa.f[1], vf1, oacc[dt], 0, 0, 0);
        }
    }

    // l: combine lane-halves (thread covers 16 of its wave's 32 j rows)
    lacc += __shfl_xor(lacc, 32, 64);
    __syncthreads();   // staging reads done; reuse smem as epilogue buffers
    if (h == 0) llds[jh * 64 + ih * 32 + l31] = lacc;
    #pragma unroll
    for (int dt = 0; dt < 2; dt++)
        #pragma unroll
        for (int r = 0; r < 16; r++) {
            int row = ih * 32 + (r & 3) + 8 * (r >> 2) + 4 * h;
            obuf[jh * 4224 + row * 66 + dt * 32 + l31] = oacc[dt][r];
        }
    __syncthreads();
    // merge jh partials, normalize, pack, store ao[b][i0+row][hh*64 + d]
    int row = tid >> 2, dch = (tid & 3) * 16;
    float linv = 1.f / (llds[row] + llds[64 + row]);
    int bb = bh >> 3, hh = bh & 7;
    ushort_t* aob = ao + ((size_t)bb * 1024 + i0 + row) * 512 + hh * 64 + dch;
    float4 r0 = *(const float4*)(obuf + row * 66 + dch + 0);
    float4 r1 = *(const float4*)(obuf + row * 66 + dch + 4);
    float4 r2 = *(const float4*)(obuf + row * 66 + dch + 8);
    float4 r3 = *(const float4*)(obuf + row * 66 + dch + 12);
    float4 s0 = *(const float4*)(obuf + 4224 + row * 66 + dch + 0);
    float4 s1 = *(const float4*)(obuf + 4224 + row * 66 + dch + 4);
    float4 s2 = *(const float4*)(obuf + 4224 + row * 66 + dch + 8);
    float4 s3 = *(const float4*)(obuf + 4224 + row * 66 + dch + 12);
    uint4 o0, o1;
    o0.x = pk2((r0.x + s0.x) * linv, (r0.y + s0.y) * linv);
    o0.y = pk2((r0.z + s0.z) * linv, (r0.w + s0.w) * linv);
    o0.z = pk2((r1.x + s1.x) * linv, (r1.y + s1.y) * linv);
    o0.w = pk2((r1.z + s1.z) * linv, (r1.w + s1.w) * linv);
    o1.x = pk2((r2.x + s2.x) * linv, (r2.y + s2.y) * linv);
    o1.y = pk2((r2.z + s2.z) * linv, (r2.w + s2.w) * linv);
    o1.z = pk2((r3.x + s3.x) * linv, (r3.y + s3.y) * linv);
    o1.w = pk2((r3.z + s3.z) * linv, (r3.w + s3.w) * linv);
    *(uint4*)(aob)     = o0;
    *(uint4*)(aob + 8) = o1;
}

// ---------------- Final conv: 128x64 tiles, batch-per-XCD. C[o(128)][n(64)] = Wo x ao + bo + x ----------------
__global__ __launch_bounds__(256) void conv_out(const ushort_t* __restrict__ ao,
                                                const ushort_t* __restrict__ wo,
                                                const float* __restrict__ bo,
                                                const float* __restrict__ xres,
                                                float* __restrict__ out) {
    __shared__ __align__(16) char smem[34816];
    ushort_t* als = (ushort_t*)smem;           // [128][32] Wo rows o
    ushort_t* bls = (ushort_t*)(smem + 8192);  // [64][32]  ao rows n
    int tid = threadIdx.x;
    int wave = tid >> 6, lane = tid & 63, l15 = lane & 15, quad = lane >> 4;
    int wm = wave >> 1, wn = wave & 1;
    int id = blockIdx.x;
    int b = id & 7, t = id >> 3;
    int mt = t >> 4, nt = t & 15;
    int m0 = mt * 128, n0 = nt * 64;
    const ushort_t* B = ao + (size_t)b * 524288;

    f32x4 acc[4][2];
    #pragma unroll
    for (int ms = 0; ms < 4; ms++)
        #pragma unroll
        for (int ns = 0; ns < 2; ns++) acc[ms][ns] = (f32x4){0.f, 0.f, 0.f, 0.f};

    for (int k0 = 0; k0 < 512; k0 += 32) {
        #pragma unroll
        for (int rep = 0; rep < 2; rep++) {
            int cid = rep * 256 + tid;
            int r = cid >> 2, part = cid & 3;
            int sw = part ^ ((r >> 2) & 3);
            cp16(wo + (size_t)(m0 + r) * 512 + k0 + sw * 8, als + (size_t)cid * 8);
        }
        {
            int r = tid >> 2, part = tid & 3;
            int sw = part ^ ((r >> 2) & 3);
            cp16(B + (size_t)(n0 + r) * 512 + k0 + sw * 8, bls + (size_t)tid * 8);
        }
        __syncthreads();
        bf16x8 af[4], bfr[2];
        #pragma unroll
        for (int ms = 0; ms < 4; ms++) {
            int row = wm * 64 + ms * 16 + l15;
            int slot = quad ^ ((row >> 2) & 3);
            af[ms] = *(const bf16x8*)(als + row * 32 + slot * 8);
        }
        #pragma unroll
        for (int ns = 0; ns < 2; ns++) {
            int row = wn * 32 + ns * 16 + l15;
            int slot = quad ^ ((row >> 2) & 3);
            bfr[ns] = *(const bf16x8*)(bls + row * 32 + slot * 8);
        }
        #pragma unroll
        for (int ms = 0; ms < 4; ms++)
            #pragma unroll
            for (int ns = 0; ns < 2; ns++)
                acc[ms][ns] = __builtin_amdgcn_mfma_f32_16x16x32_bf16(af[ms], bfr[ns], acc[ms][ns], 0, 0, 0);
        __syncthreads();
    }

    float* clsf = (float*)smem;   // [128 o][66] f32
    #pragma unroll
    for (int ms = 0; ms < 4; ms++)
        #pragma unroll
        for (int ns = 0; ns < 2; ns++)
            #pragma unroll
            for (int r = 0; r < 4; r++)
                clsf[(wm * 64 + ms * 16 + quad * 4 + r) * 66 + wn * 32 + ns * 16 + l15] = acc[ms][ns][r];
    __syncthreads();
    #pragma unroll
    for (int rep = 0; rep < 8; rep++) {
        int cid = rep * 256 + tid;
        int row = cid >> 4, p = cid & 15;
        float bvr = bo[m0 + row];
        float4 c4 = *(const float4*)(clsf + row * 66 + p * 4);
        size_t ga = ((size_t)(b * 512 + m0 + row)) * 1024 + n0 + p * 4;
        float4 xv = *(const float4*)(xres + ga);
        c4.x += bvr + xv.x; c4.y += bvr + xv.y; c4.z += bvr + xv.z; c4.w += bvr + xv.w;
        *(float4*)(out + ga) = c4;
    }
}

extern "C" void kernel_launch(void* const* d_in, const int* in_sizes, int n_in,
                              void* d_out, int out_size, void* d_ws, size_t ws_size,
                              hipStream_t stream) {
    const float* x    = (const float*)d_in[0];
    const float* gn_w = (const float*)d_in[1];
    const float* gn_b = (const float*)d_in[2];
    const float* wq   = (const float*)d_in[3];
    const float* bq   = (const float*)d_in[4];
    const float* wk   = (const float*)d_in[5];
    const float* bk   = (const float*)d_in[6];
    const float* wv   = (const float*)d_in[7];
    const float* bv   = (const float*)d_in[8];
    const float* wo   = (const float*)d_in[9];
    const float* bo   = (const float*)d_in[10];

    char* ws = (char*)d_ws;
    ushort_t* xnt  = (ushort_t*)(ws);                        // 8 MB  [b][n][c]
    ushort_t* qt   = (ushort_t*)(ws + (((size_t)8)  << 20)); // 8 MB  [bh][n][d] (pre-scaled)
    ushort_t* kt   = (ushort_t*)(ws + (((size_t)16) << 20)); // 8 MB  [bh][n][d]
    ushort_t* vt   = (ushort_t*)(ws + (((size_t)24) << 20)); // 8 MB  [b][c][n]
    ushort_t* wbf  = (ushort_t*)(ws + (((size_t)32) << 20)); // 2 MB  Wq|Wk|Wv|Wo bf16
    float2*   gst  = (float2*)  (ws + (((size_t)34) << 20)); // 2 KB  stats
    ushort_t* ao   = xnt;   // attn output reuses xnt

    prep_kernel<<<1280, 256, 0, stream>>>(x, wq, wk, wv, wo, gst, wbf);
    gn_apply<<<dim3(4, 256), 256, 0, stream>>>(x, gn_w, gn_b, gst, xnt);

    conv_qkv<<<768, 256, 0, stream>>>(xnt, wbf, bq, bk, bv, qt, kt, vt);

    attn_kernel<<<1024, 256, 0, stream>>>(qt, kt, vt, ao);

    conv_out<<<512, 256, 0, stream>>>(ao, wbf + 786432, bo, x, (float*)d_out);
}